// Round 3
// baseline (784.102 us; speedup 1.0000x reference)
//
#include <hip/hip_runtime.h>
#include <hip/hip_bf16.h>
#include <math.h>

#define N_TOK   2048
#define HIDDEN  1024
#define INTER   2816
#define NEXP    8
#define NADAPT  2
#define MAXRANK 16
#define TOPK    2
#define NSEQ    8
#define NPAIRS  (N_TOK*TOPK)     // 4096
#define NGU     (2*INTER)        // 5632

typedef unsigned short u16;
typedef __attribute__((ext_vector_type(8))) short bf16x8;
typedef __attribute__((ext_vector_type(4))) float f32x4;

// ---- workspace layout (bytes) ---- total ~24.1 MB
#define OFF_CNT   0u
#define OFF_PERM  4096u       // 8*4096*4 = 131072
#define OFF_ZG    262144u     // 4096*32*2 = 262144
#define OFF_ZU    524288u
#define OFF_ZD    786432u
#define OFF_ACT   1048576u    // 4096*2816*2 = 23068672 -> ends ~24.1MB

__device__ __forceinline__ float bf2f(u16 u){
  union { unsigned int i; float f; } v; v.i = ((unsigned int)u)<<16; return v.f;
}
__device__ __forceinline__ u16 f2bf(float f){
  union { float f; unsigned int i; } v; v.f = f;
  unsigned int i = v.i;
  return (u16)((i + 0x7fffu + ((i>>16)&1u)) >> 16);
}
// 8 consecutive f32 -> 8 bf16 packed in a uint4 (for 16B LDS store)
__device__ __forceinline__ uint4 cvt8(const float* src){
  float4 lo = *(const float4*)src;
  float4 hi = *(const float4*)(src+4);
  uint4 r;
  r.x = (unsigned)f2bf(lo.x) | ((unsigned)f2bf(lo.y)<<16);
  r.y = (unsigned)f2bf(lo.z) | ((unsigned)f2bf(lo.w)<<16);
  r.z = (unsigned)f2bf(hi.x) | ((unsigned)f2bf(hi.y)<<16);
  r.w = (unsigned)f2bf(hi.z) | ((unsigned)f2bf(hi.w)<<16);
  return r;
}

__device__ __forceinline__ int token_adapter(int n, const int* seq_lens, const int* widx){
  int cum = 0;
  #pragma unroll
  for (int s = 0; s < NSEQ; ++s){ cum += seq_lens[s]; if (n < cum) return widx[s]; }
  return widx[NSEQ-1];
}

// zero d_out (2M f32) and cnt
__global__ void k_zero(float* outf, int* cnt){
  int id = blockIdx.x*256 + threadIdx.x;
  *(float4*)&outf[(size_t)id*4] = make_float4(0.f,0.f,0.f,0.f);
  if (blockIdx.x == 0 && threadIdx.x < NEXP) cnt[threadIdx.x] = 0;
}

__global__ void k_route(const int* __restrict__ topk_ids, int* cnt, int* perm){
  int p = blockIdx.x*256 + threadIdx.x;
  if (p >= NPAIRS) return;
  int e = topk_ids[p];
  int pos = atomicAdd(&cnt[e], 1);
  perm[e*NPAIRS + pos] = p;
}

// z' for gate & up: zg/zu[p][32] bf16, slot a*16+r = scale*mask(r<rank)*dot(x[n], A[a,e,r,:])
__global__ __launch_bounds__(256) void k_zgu(
    const float* __restrict__ x, const int* __restrict__ topk_ids,
    const float* __restrict__ gate_a, const float* __restrict__ up_a,
    const int* __restrict__ widx, const int* __restrict__ seq_lens,
    const int* __restrict__ ranks, const float* __restrict__ scal,
    u16* __restrict__ zg, u16* __restrict__ zu)
{
  int p = blockIdx.x, n = p >> 1, t = threadIdx.x;
  int e = topk_ids[p];
  __shared__ float xs[HIDDEN];
  for (int i = t; i < HIDDEN; i += 256) xs[i] = x[(size_t)n*HIDDEN + i];
  if (t < 32){ zg[p*32 + t] = 0; zu[p*32 + t] = 0; }
  __syncthreads();
  int a = token_adapter(n, seq_lens, widx);
  int rank = ranks[a];
  float scale = scal[a];
  int wv = t >> 6, lane = t & 63;
  for (int i = 0; i < 8; ++i){
    int o = wv*8 + i;              // 0..31: 0-15 gate r, 16-31 up r
    int r = o & 15;
    const float* wrow = ((o < 16) ? gate_a : up_a) + (size_t)((a*NEXP + e)*MAXRANK + r)*HIDDEN;
    float s = 0.f;
    for (int h = lane; h < HIDDEN; h += 64) s += xs[h] * wrow[h];
    s += __shfl_down(s,32); s += __shfl_down(s,16); s += __shfl_down(s,8);
    s += __shfl_down(s,4);  s += __shfl_down(s,2);  s += __shfl_down(s,1);
    if (lane == 0 && r < rank)
      (o < 16 ? zg : zu)[p*32 + a*16 + r] = f2bf(scale * s);
  }
}

// z' for down: zd[p][32] from act[p][:2816] (act is bf16)
__global__ __launch_bounds__(256) void k_zd(
    const u16* __restrict__ act, const int* __restrict__ topk_ids,
    const float* __restrict__ down_a,
    const int* __restrict__ widx, const int* __restrict__ seq_lens,
    const int* __restrict__ ranks, const float* __restrict__ scal,
    u16* __restrict__ zd)
{
  int p = blockIdx.x, n = p >> 1, t = threadIdx.x;
  int e = topk_ids[p];
  __shared__ float as_[INTER];
  for (int i = t; i < INTER; i += 256) as_[i] = bf2f(act[(size_t)p*INTER + i]);
  if (t < 32) zd[p*32 + t] = 0;
  __syncthreads();
  int a = token_adapter(n, seq_lens, widx);
  int rank = ranks[a];
  float scale = scal[a];
  int wv = t >> 6, lane = t & 63;
  for (int i = 0; i < 4; ++i){
    int r = wv*4 + i;
    const float* wrow = down_a + (size_t)((a*NEXP + e)*MAXRANK + r)*INTER;
    float s = 0.f;
    for (int h = lane; h < INTER; h += 64) s += as_[h] * wrow[h];
    s += __shfl_down(s,32); s += __shfl_down(s,16); s += __shfl_down(s,8);
    s += __shfl_down(s,4);  s += __shfl_down(s,2);  s += __shfl_down(s,1);
    if (lane == 0 && r < rank) zd[p*32 + a*16 + r] = f2bf(scale * s);
  }
}

// Fused GEMM1: per block, 128 pairs x 64 inter-cols; computes BOTH gate and up
// (K = 1024 base + 32 LoRA), then act = silu(gate)*up written as bf16.
__global__ __launch_bounds__(256) void k_gufused(
    const float* __restrict__ x, const float* __restrict__ wgu,
    const float* __restrict__ gate_b, const float* __restrict__ up_b,
    const u16* __restrict__ zg, const u16* __restrict__ zu,
    const int* __restrict__ cnt, const int* __restrict__ perm,
    u16* __restrict__ act)
{
  int e = blockIdx.z;
  int me = cnt[e];
  int tm = blockIdx.y;
  if (tm*128 >= me) return;
  int tn = blockIdx.x;            // 0..43 : 64 inter-columns each
  int t = threadIdx.x;

  __shared__ u16 As[128*32];
  __shared__ u16 Bg[64*32];
  __shared__ u16 Bu[64*32];

  int r0 = t >> 2, cc = t & 3;    // r0: 0..63, cc: 0..3 (8 elems each)
  int mg0 = tm*128 + r0, mg1 = mg0 + 64;
  int p0 = perm[e*NPAIRS + min(mg0, me-1)];
  int p1 = perm[e*NPAIRS + min(mg1, me-1)];
  const float* arow0 = x + (size_t)(p0 >> 1)*HIDDEN;
  const float* arow1 = x + (size_t)(p1 >> 1)*HIDDEN;
  int jg = tn*64 + r0;            // inter column this thread stages (0..2815)
  const float* browg = wgu + ((size_t)e*NGU + jg)*HIDDEN;
  const float* browu = wgu + ((size_t)e*NGU + INTER + jg)*HIDDEN;

  int wv = t >> 6, lane = t & 63;
  int wm = wv >> 1, wn = wv & 1;  // 2x2 waves: wave tile 64 pairs x 32 cols

  f32x4 accg[4][2] = {};
  f32x4 accu[4][2] = {};
  int aoff[4], boff[2];
  #pragma unroll
  for (int i = 0; i < 4; ++i) aoff[i] = (wm*64 + i*16 + (lane&15))*32 + (lane>>4)*8;
  #pragma unroll
  for (int j = 0; j < 2; ++j) boff[j] = (wn*32 + j*16 + (lane&15))*32 + (lane>>4)*8;

  for (int kt = 0; kt < HIDDEN/32; ++kt){
    uint4 a0 = cvt8(arow0 + kt*32 + cc*8);
    uint4 a1 = cvt8(arow1 + kt*32 + cc*8);
    uint4 bg = cvt8(browg + kt*32 + cc*8);
    uint4 bu = cvt8(browu + kt*32 + cc*8);
    __syncthreads();
    *(uint4*)&As[r0*32 + cc*8]      = a0;
    *(uint4*)&As[(r0+64)*32 + cc*8] = a1;
    *(uint4*)&Bg[r0*32 + cc*8]      = bg;
    *(uint4*)&Bu[r0*32 + cc*8]      = bu;
    __syncthreads();
    bf16x8 af[4], bgf[2], buf[2];
    #pragma unroll
    for (int i = 0; i < 4; ++i) af[i] = *(const bf16x8*)&As[aoff[i]];
    #pragma unroll
    for (int j = 0; j < 2; ++j){ bgf[j] = *(const bf16x8*)&Bg[boff[j]]; buf[j] = *(const bf16x8*)&Bu[boff[j]]; }
    #pragma unroll
    for (int i = 0; i < 4; ++i)
      #pragma unroll
      for (int j = 0; j < 2; ++j){
        accg[i][j] = __builtin_amdgcn_mfma_f32_16x16x32_bf16(af[i], bgf[j], accg[i][j], 0, 0, 0);
        accu[i][j] = __builtin_amdgcn_mfma_f32_16x16x32_bf16(af[i], buf[j], accu[i][j], 0, 0, 0);
      }
  }

  // LoRA extension for GATE: As <- zg (bf16, slot a*16+r), Bg <- gate_b (f32)
  {
    uint4 a0 = *(const uint4*)(zg + (size_t)p0*32 + cc*8);
    uint4 a1 = *(const uint4*)(zg + (size_t)p1*32 + cc*8);
    int aid = cc >> 1, rr = (cc & 1)*8;
    uint4 bg = cvt8(gate_b + ((size_t)(aid*NEXP + e)*INTER + jg)*MAXRANK + rr);
    __syncthreads();
    *(uint4*)&As[r0*32 + cc*8]      = a0;
    *(uint4*)&As[(r0+64)*32 + cc*8] = a1;
    *(uint4*)&Bg[r0*32 + cc*8]      = bg;
    __syncthreads();
    bf16x8 af[4], bgf[2];
    #pragma unroll
    for (int i = 0; i < 4; ++i) af[i] = *(const bf16x8*)&As[aoff[i]];
    #pragma unroll
    for (int j = 0; j < 2; ++j) bgf[j] = *(const bf16x8*)&Bg[boff[j]];
    #pragma unroll
    for (int i = 0; i < 4; ++i)
      #pragma unroll
      for (int j = 0; j < 2; ++j)
        accg[i][j] = __builtin_amdgcn_mfma_f32_16x16x32_bf16(af[i], bgf[j], accg[i][j], 0, 0, 0);
  }
  // LoRA extension for UP: As <- zu, Bg buffer reused <- up_b
  {
    uint4 a0 = *(const uint4*)(zu + (size_t)p0*32 + cc*8);
    uint4 a1 = *(const uint4*)(zu + (size_t)p1*32 + cc*8);
    int aid = cc >> 1, rr = (cc & 1)*8;
    uint4 bu = cvt8(up_b + ((size_t)(aid*NEXP + e)*INTER + jg)*MAXRANK + rr);
    __syncthreads();
    *(uint4*)&As[r0*32 + cc*8]      = a0;
    *(uint4*)&As[(r0+64)*32 + cc*8] = a1;
    *(uint4*)&Bg[r0*32 + cc*8]      = bu;
    __syncthreads();
    bf16x8 af[4], buf[2];
    #pragma unroll
    for (int i = 0; i < 4; ++i) af[i] = *(const bf16x8*)&As[aoff[i]];
    #pragma unroll
    for (int j = 0; j < 2; ++j) buf[j] = *(const bf16x8*)&Bg[boff[j]];
    #pragma unroll
    for (int i = 0; i < 4; ++i)
      #pragma unroll
      for (int j = 0; j < 2; ++j)
        accu[i][j] = __builtin_amdgcn_mfma_f32_16x16x32_bf16(af[i], buf[j], accu[i][j], 0, 0, 0);
  }

  // epilogue: act = silu(gate) * up   (C/D map: col=lane&15, row=quad*4+reg)
  int col = lane & 15, quad = lane >> 4;
  #pragma unroll
  for (int i = 0; i < 4; ++i){
    #pragma unroll
    for (int r = 0; r < 4; ++r){
      int mg = tm*128 + wm*64 + i*16 + quad*4 + r;
      if (mg < me){
        int p = perm[e*NPAIRS + mg];
        size_t base = (size_t)p*INTER;
        #pragma unroll
        for (int j = 0; j < 2; ++j){
          int jc = tn*64 + wn*32 + j*16 + col;
          float g = accg[i][j][r], u = accu[i][j][r];
          float s = g / (1.f + __expf(-g));
          act[base + jc] = f2bf(s*u);
        }
      }
    }
  }
}

// GEMM2: down proj (K = 2816 + 32), epilogue atomicAdd of w_p * val into outf[n][h]
__global__ __launch_bounds__(256) void k_gemm_down(
    const u16* __restrict__ act, const float* __restrict__ wd,
    const float* __restrict__ down_b, const u16* __restrict__ zd,
    const float* __restrict__ tw,
    const int* __restrict__ cnt, const int* __restrict__ perm,
    float* __restrict__ outf)
{
  int e = blockIdx.z;
  int me = cnt[e];
  int tm = blockIdx.y;
  if (tm*128 >= me) return;
  int tn = blockIdx.x;
  int t = threadIdx.x;

  __shared__ u16 As[128*32];
  __shared__ u16 Bs[128*32];

  int r0 = t >> 2, cc = t & 3;
  int mg0 = tm*128 + r0, mg1 = mg0 + 64;
  int p0 = perm[e*NPAIRS + min(mg0, me-1)];
  int p1 = perm[e*NPAIRS + min(mg1, me-1)];
  const u16* arow0 = act + (size_t)p0*INTER;
  const u16* arow1 = act + (size_t)p1*INTER;
  int j0 = tn*128 + r0, j1 = j0 + 64;
  const float* brow0 = wd + ((size_t)e*HIDDEN + j0)*INTER;
  const float* brow1 = wd + ((size_t)e*HIDDEN + j1)*INTER;

  int wv = t >> 6, lane = t & 63;
  int wm = wv >> 1, wn = wv & 1;

  f32x4 acc[4][4] = {};
  int aoff[4], boff[4];
  #pragma unroll
  for (int i = 0; i < 4; ++i){
    aoff[i] = (wm*64 + i*16 + (lane&15))*32 + (lane>>4)*8;
    boff[i] = (wn*64 + i*16 + (lane&15))*32 + (lane>>4)*8;
  }

  auto compute = [&](){
    bf16x8 af[4], bfr[4];
    #pragma unroll
    for (int i = 0; i < 4; ++i){
      af[i]  = *(const bf16x8*)&As[aoff[i]];
      bfr[i] = *(const bf16x8*)&Bs[boff[i]];
    }
    #pragma unroll
    for (int i = 0; i < 4; ++i)
      #pragma unroll
      for (int j = 0; j < 4; ++j)
        acc[i][j] = __builtin_amdgcn_mfma_f32_16x16x32_bf16(af[i], bfr[j], acc[i][j], 0, 0, 0);
  };

  for (int kt = 0; kt < INTER/32; ++kt){
    uint4 a0 = *(const uint4*)(arow0 + kt*32 + cc*8);   // act is bf16 already
    uint4 a1 = *(const uint4*)(arow1 + kt*32 + cc*8);
    uint4 b0 = cvt8(brow0 + kt*32 + cc*8);
    uint4 b1 = cvt8(brow1 + kt*32 + cc*8);
    __syncthreads();
    *(uint4*)&As[r0*32 + cc*8]      = a0;
    *(uint4*)&As[(r0+64)*32 + cc*8] = a1;
    *(uint4*)&Bs[r0*32 + cc*8]      = b0;
    *(uint4*)&Bs[(r0+64)*32 + cc*8] = b1;
    __syncthreads();
    compute();
  }
  { // LoRA extension
    uint4 a0 = *(const uint4*)(zd + (size_t)p0*32 + cc*8);
    uint4 a1 = *(const uint4*)(zd + (size_t)p1*32 + cc*8);
    int aid = cc >> 1, rr = (cc & 1)*8;
    uint4 b0 = cvt8(down_b + ((size_t)(aid*NEXP + e)*HIDDEN + j0)*MAXRANK + rr);
    uint4 b1 = cvt8(down_b + ((size_t)(aid*NEXP + e)*HIDDEN + j1)*MAXRANK + rr);
    __syncthreads();
    *(uint4*)&As[r0*32 + cc*8]      = a0;
    *(uint4*)&As[(r0+64)*32 + cc*8] = a1;
    *(uint4*)&Bs[r0*32 + cc*8]      = b0;
    *(uint4*)&Bs[(r0+64)*32 + cc*8] = b1;
    __syncthreads();
    compute();
  }
  int col = lane & 15, quad = lane >> 4;
  #pragma unroll
  for (int i = 0; i < 4; ++i){
    #pragma unroll
    for (int r = 0; r < 4; ++r){
      int mg = tm*128 + wm*64 + i*16 + quad*4 + r;
      if (mg < me){
        int p = perm[e*NPAIRS + mg];
        float wp = tw[p];
        size_t base = (size_t)(p >> 1)*HIDDEN;
        #pragma unroll
        for (int j = 0; j < 4; ++j){
          int jc = tn*128 + wn*64 + j*16 + col;
          atomicAdd(&outf[base + jc], wp * acc[i][j][r]);
        }
      }
    }
  }
}

extern "C" void kernel_launch(void* const* d_in, const int* in_sizes, int n_in,
                              void* d_out, int out_size, void* d_ws, size_t ws_size,
                              hipStream_t stream){
  const float* x        = (const float*)d_in[0];
  const int*   topk_ids = (const int*)d_in[1];
  const float* tw       = (const float*)d_in[2];
  const float* gate_a   = (const float*)d_in[3];
  const float* gate_b   = (const float*)d_in[4];
  const float* up_a     = (const float*)d_in[5];
  const float* up_b     = (const float*)d_in[6];
  const float* down_a   = (const float*)d_in[7];
  const float* down_b   = (const float*)d_in[8];
  const int*   widx     = (const int*)d_in[9];
  const int*   seq_lens = (const int*)d_in[10];
  const int*   ranks    = (const int*)d_in[11];
  const float* scal     = (const float*)d_in[12];
  const float* wgu      = (const float*)d_in[13];
  const float* wd       = (const float*)d_in[14];
  float* outf = (float*)d_out;
  char* ws = (char*)d_ws;
  int* cnt  = (int*)(ws + OFF_CNT);
  int* perm = (int*)(ws + OFF_PERM);
  u16* zg   = (u16*)(ws + OFF_ZG);
  u16* zu   = (u16*)(ws + OFF_ZU);
  u16* zd   = (u16*)(ws + OFF_ZD);
  u16* act  = (u16*)(ws + OFF_ACT);

  hipLaunchKernelGGL(k_zero,  dim3(N_TOK*HIDDEN/1024), dim3(256), 0, stream, outf, cnt);
  hipLaunchKernelGGL(k_route, dim3(16), dim3(256), 0, stream, topk_ids, cnt, perm);
  hipLaunchKernelGGL(k_zgu,   dim3(NPAIRS), dim3(256), 0, stream,
                     x, topk_ids, gate_a, up_a, widx, seq_lens, ranks, scal, zg, zu);
  hipLaunchKernelGGL(k_gufused, dim3(INTER/64, 32, NEXP), dim3(256), 0, stream,
                     x, wgu, gate_b, up_b, zg, zu, cnt, perm, act);
  hipLaunchKernelGGL(k_zd,    dim3(NPAIRS), dim3(256), 0, stream,
                     act, topk_ids, down_a, widx, seq_lens, ranks, scal, zd);
  hipLaunchKernelGGL(k_gemm_down, dim3(HIDDEN/128, 32, NEXP), dim3(256), 0, stream,
                     act, wd, down_b, zd, tw, cnt, perm, outf);
}

// Round 4
// 764.958 us; speedup vs baseline: 1.0250x; 1.0250x over previous
//
#include <hip/hip_runtime.h>
#include <hip/hip_bf16.h>
#include <math.h>

#define N_TOK   2048
#define HIDDEN  1024
#define INTER   2816
#define NEXP    8
#define NADAPT  2
#define MAXRANK 16
#define TOPK    2
#define NSEQ    8
#define NPAIRS  (N_TOK*TOPK)     // 4096
#define NGU     (2*INTER)        // 5632

typedef unsigned short u16;
typedef __attribute__((ext_vector_type(8))) short bf16x8;
typedef __attribute__((ext_vector_type(4))) float f32x4;

// ---- FAST workspace layout (bytes), needs ~164 MB ----
#define F_CNT   0u
#define F_PERM  4096u        // 131072
#define F_ZG    139264u      // 262144
#define F_ZU    401408u
#define F_ZD    663552u
#define F_XBF   1048576u     // 4194304
#define F_ACT   5242880u     // 23068672
#define F_GB    28311552u    // 1441792
#define F_UB    29753344u    // 1441792
#define F_DB    31195136u    // 524288
#define F_WGU   33554432u    // 92274688
#define F_WD    125829120u   // 46137344 -> ends 171966464
#define FAST_NEED 171966464u

// ---- fallback (round-3) layout, ~24.1 MB ----
#define B_CNT   0u
#define B_PERM  4096u
#define B_ZG    262144u
#define B_ZU    524288u
#define B_ZD    786432u
#define B_ACT   1048576u

__device__ __forceinline__ float bf2f(u16 u){
  union { unsigned int i; float f; } v; v.i = ((unsigned int)u)<<16; return v.f;
}
__device__ __forceinline__ u16 f2bf(float f){
  union { float f; unsigned int i; } v; v.f = f;
  unsigned int i = v.i;
  return (u16)((i + 0x7fffu + ((i>>16)&1u)) >> 16);
}
__device__ __forceinline__ uint4 cvt8(const float* src){
  float4 lo = *(const float4*)src;
  float4 hi = *(const float4*)(src+4);
  uint4 r;
  r.x = (unsigned)f2bf(lo.x) | ((unsigned)f2bf(lo.y)<<16);
  r.y = (unsigned)f2bf(lo.z) | ((unsigned)f2bf(lo.w)<<16);
  r.z = (unsigned)f2bf(hi.x) | ((unsigned)f2bf(hi.y)<<16);
  r.w = (unsigned)f2bf(hi.z) | ((unsigned)f2bf(hi.w)<<16);
  return r;
}

// async 16B global -> LDS (wave-uniform LDS base + lane*16)
__device__ __forceinline__ void gl16(const void* g, void* l){
  __builtin_amdgcn_global_load_lds(
      (const __attribute__((address_space(1))) unsigned int*)g,
      (__attribute__((address_space(3))) unsigned int*)l, 16, 0, 0);
}

__device__ __forceinline__ int token_adapter(int n, const int* seq_lens, const int* widx){
  int cum = 0;
  #pragma unroll
  for (int s = 0; s < NSEQ; ++s){ cum += seq_lens[s]; if (n < cum) return widx[s]; }
  return widx[NSEQ-1];
}

__global__ void k_zero(float* outf, int* cnt){
  int id = blockIdx.x*256 + threadIdx.x;
  *(float4*)&outf[(size_t)id*4] = make_float4(0.f,0.f,0.f,0.f);
  if (blockIdx.x == 0 && threadIdx.x < NEXP) cnt[threadIdx.x] = 0;
}

__global__ void k_route(const int* __restrict__ topk_ids, int* cnt, int* perm){
  int p = blockIdx.x*256 + threadIdx.x;
  if (p >= NPAIRS) return;
  int e = topk_ids[p];
  int pos = atomicAdd(&cnt[e], 1);
  perm[e*NPAIRS + pos] = p;
}

// f32 -> bf16, 8 elems/thread
__global__ void k_cvt(const float* __restrict__ src, u16* __restrict__ dst, int n8){
  int id = blockIdx.x*256 + threadIdx.x;
  if (id >= n8) return;
  *(uint4*)&dst[(size_t)id*8] = cvt8(src + (size_t)id*8);
}

// z' for gate & up (f32 weights; shared by both paths)
__global__ __launch_bounds__(256) void k_zgu(
    const float* __restrict__ x, const int* __restrict__ topk_ids,
    const float* __restrict__ gate_a, const float* __restrict__ up_a,
    const int* __restrict__ widx, const int* __restrict__ seq_lens,
    const int* __restrict__ ranks, const float* __restrict__ scal,
    u16* __restrict__ zg, u16* __restrict__ zu)
{
  int p = blockIdx.x, n = p >> 1, t = threadIdx.x;
  int e = topk_ids[p];
  __shared__ float xs[HIDDEN];
  for (int i = t; i < HIDDEN; i += 256) xs[i] = x[(size_t)n*HIDDEN + i];
  if (t < 32){ zg[p*32 + t] = 0; zu[p*32 + t] = 0; }
  __syncthreads();
  int a = token_adapter(n, seq_lens, widx);
  int rank = ranks[a];
  float scale = scal[a];
  int wv = t >> 6, lane = t & 63;
  for (int i = 0; i < 8; ++i){
    int o = wv*8 + i;
    int r = o & 15;
    const float* wrow = ((o < 16) ? gate_a : up_a) + (size_t)((a*NEXP + e)*MAXRANK + r)*HIDDEN;
    float s = 0.f;
    for (int h = lane; h < HIDDEN; h += 64) s += xs[h] * wrow[h];
    s += __shfl_down(s,32); s += __shfl_down(s,16); s += __shfl_down(s,8);
    s += __shfl_down(s,4);  s += __shfl_down(s,2);  s += __shfl_down(s,1);
    if (lane == 0 && r < rank)
      (o < 16 ? zg : zu)[p*32 + a*16 + r] = f2bf(scale * s);
  }
}

__global__ __launch_bounds__(256) void k_zd(
    const u16* __restrict__ act, const int* __restrict__ topk_ids,
    const float* __restrict__ down_a,
    const int* __restrict__ widx, const int* __restrict__ seq_lens,
    const int* __restrict__ ranks, const float* __restrict__ scal,
    u16* __restrict__ zd)
{
  int p = blockIdx.x, n = p >> 1, t = threadIdx.x;
  int e = topk_ids[p];
  __shared__ float as_[INTER];
  for (int i = t; i < INTER; i += 256) as_[i] = bf2f(act[(size_t)p*INTER + i]);
  if (t < 32) zd[p*32 + t] = 0;
  __syncthreads();
  int a = token_adapter(n, seq_lens, widx);
  int rank = ranks[a];
  float scale = scal[a];
  int wv = t >> 6, lane = t & 63;
  for (int i = 0; i < 4; ++i){
    int r = wv*4 + i;
    const float* wrow = down_a + (size_t)((a*NEXP + e)*MAXRANK + r)*INTER;
    float s = 0.f;
    for (int h = lane; h < INTER; h += 64) s += as_[h] * wrow[h];
    s += __shfl_down(s,32); s += __shfl_down(s,16); s += __shfl_down(s,8);
    s += __shfl_down(s,4);  s += __shfl_down(s,2);  s += __shfl_down(s,1);
    if (lane == 0 && r < rank) zd[p*32 + a*16 + r] = f2bf(scale * s);
  }
}

// ===================== FAST PATH GEMMs (bf16 inputs, global_load_lds, swizzled LDS) =====================
// LDS chunk swizzle: 16B chunk of (row, kc) stored at slot row*4 + ((kc+row)&3).
// Staging thread t covers slot t (and t+256): row=t>>2, fetches kc=((t&3)-(t>>2))&3.
// Read of (row, kc=q): elem offset row*32 + ((q+row)&3)*8 -> bank-balanced per 32-lane phase.

__global__ __launch_bounds__(256) void k_gufused_bf(
    const u16* __restrict__ xb, const u16* __restrict__ wgu,
    const u16* __restrict__ gbb, const u16* __restrict__ ubb,
    const u16* __restrict__ zg, const u16* __restrict__ zu,
    const int* __restrict__ cnt, const int* __restrict__ perm,
    u16* __restrict__ act)
{
  int e = blockIdx.z;
  int me = cnt[e];
  int tm = blockIdx.y;
  if (tm*128 >= me) return;
  int tn = blockIdx.x;            // 0..43, 64 inter-cols each
  int t = threadIdx.x;

  __shared__ __align__(16) u16 As[128*32];
  __shared__ __align__(16) u16 Bg[64*32];
  __shared__ __align__(16) u16 Bu[64*32];

  int r0 = t >> 2;
  int kc = ((t&3) - r0) & 3;      // logical k-chunk this thread fetches
  int ko = kc*8;
  int mg0 = tm*128 + r0, mg1 = mg0 + 64;
  int p0 = perm[e*NPAIRS + min(mg0, me-1)];
  int p1 = perm[e*NPAIRS + min(mg1, me-1)];
  const u16* arow0 = xb + (size_t)(p0>>1)*HIDDEN + ko;
  const u16* arow1 = xb + (size_t)(p1>>1)*HIDDEN + ko;
  int jg = tn*64 + r0;
  const u16* browg = wgu + ((size_t)e*NGU + jg)*HIDDEN + ko;
  const u16* browu = wgu + ((size_t)e*NGU + INTER + jg)*HIDDEN + ko;

  int wvb = (t>>6)*512;           // wave's 1KB LDS chunk base (in elems)
  u16* Asw0 = &As[wvb];
  u16* Asw1 = &As[2048 + wvb];
  u16* Bgw  = &Bg[wvb];
  u16* Buw  = &Bu[wvb];

  int wv = t>>6, lane = t&63;
  int wm = wv>>1, wn = wv&1;
  int l15 = lane&15, q = lane>>4;

  f32x4 accg[4][2] = {};
  f32x4 accu[4][2] = {};
  int aoff[4], boff[2];
  #pragma unroll
  for (int i=0;i<4;++i){ int row = wm*64 + i*16 + l15; aoff[i] = row*32 + ((q+row)&3)*8; }
  #pragma unroll
  for (int j=0;j<2;++j){ int row = wn*32 + j*16 + l15; boff[j] = row*32 + ((q+row)&3)*8; }

  for (int kt = 0; kt < HIDDEN/32; ++kt){
    __syncthreads();
    gl16(arow0 + kt*32, Asw0);
    gl16(arow1 + kt*32, Asw1);
    gl16(browg + kt*32, Bgw);
    gl16(browu + kt*32, Buw);
    __syncthreads();
    bf16x8 af[4], bgf[2], buf[2];
    #pragma unroll
    for (int i=0;i<4;++i) af[i] = *(const bf16x8*)&As[aoff[i]];
    #pragma unroll
    for (int j=0;j<2;++j){ bgf[j] = *(const bf16x8*)&Bg[boff[j]]; buf[j] = *(const bf16x8*)&Bu[boff[j]]; }
    #pragma unroll
    for (int i=0;i<4;++i)
      #pragma unroll
      for (int j=0;j<2;++j){
        accg[i][j] = __builtin_amdgcn_mfma_f32_16x16x32_bf16(af[i], bgf[j], accg[i][j],0,0,0);
        accu[i][j] = __builtin_amdgcn_mfma_f32_16x16x32_bf16(af[i], buf[j], accu[i][j],0,0,0);
      }
  }
  // LoRA K-extension (32 = NADAPT*MAXRANK); gate uses zg, up uses zu
  {
    int aid = kc>>1, rr = (kc&1)*8;
    const u16* gB = gbb + ((size_t)(aid*NEXP+e)*INTER + jg)*MAXRANK + rr;
    const u16* uB = ubb + ((size_t)(aid*NEXP+e)*INTER + jg)*MAXRANK + rr;
    __syncthreads();
    gl16(zg + (size_t)p0*32 + ko, Asw0);
    gl16(zg + (size_t)p1*32 + ko, Asw1);
    gl16(gB, Bgw);
    __syncthreads();
    {
      bf16x8 af[4], bgf[2];
      #pragma unroll
      for (int i=0;i<4;++i) af[i] = *(const bf16x8*)&As[aoff[i]];
      #pragma unroll
      for (int j=0;j<2;++j) bgf[j] = *(const bf16x8*)&Bg[boff[j]];
      #pragma unroll
      for (int i=0;i<4;++i)
        #pragma unroll
        for (int j=0;j<2;++j)
          accg[i][j] = __builtin_amdgcn_mfma_f32_16x16x32_bf16(af[i], bgf[j], accg[i][j],0,0,0);
    }
    __syncthreads();
    gl16(zu + (size_t)p0*32 + ko, Asw0);
    gl16(zu + (size_t)p1*32 + ko, Asw1);
    gl16(uB, Bgw);                       // reuse Bg buffer
    __syncthreads();
    {
      bf16x8 af[4], buf[2];
      #pragma unroll
      for (int i=0;i<4;++i) af[i] = *(const bf16x8*)&As[aoff[i]];
      #pragma unroll
      for (int j=0;j<2;++j) buf[j] = *(const bf16x8*)&Bg[boff[j]];
      #pragma unroll
      for (int i=0;i<4;++i)
        #pragma unroll
        for (int j=0;j<2;++j)
          accu[i][j] = __builtin_amdgcn_mfma_f32_16x16x32_bf16(af[i], buf[j], accu[i][j],0,0,0);
    }
  }

  int col = l15, quad = q;
  #pragma unroll
  for (int i = 0; i < 4; ++i){
    #pragma unroll
    for (int r = 0; r < 4; ++r){
      int mg = tm*128 + wm*64 + i*16 + quad*4 + r;
      if (mg < me){
        int p = perm[e*NPAIRS + mg];
        size_t base = (size_t)p*INTER;
        #pragma unroll
        for (int j = 0; j < 2; ++j){
          int jc = tn*64 + wn*32 + j*16 + col;
          float g = accg[i][j][r], u = accu[i][j][r];
          float s = g / (1.f + __expf(-g));
          act[base + jc] = f2bf(s*u);
        }
      }
    }
  }
}

// down GEMM, split-K x4 (kt chunks of 22; LoRA tile on ks==3)
__global__ __launch_bounds__(256) void k_down_bf(
    const u16* __restrict__ act, const u16* __restrict__ wdb,
    const u16* __restrict__ dbb, const u16* __restrict__ zd,
    const float* __restrict__ tw,
    const int* __restrict__ cnt, const int* __restrict__ perm,
    float* __restrict__ outf)
{
  int e = blockIdx.z;
  int me = cnt[e];
  int tm = blockIdx.y;
  if (tm*128 >= me) return;
  int tn = blockIdx.x & 7;
  int ks = blockIdx.x >> 3;       // 0..3
  int t = threadIdx.x;

  __shared__ __align__(16) u16 As[128*32];
  __shared__ __align__(16) u16 Bs[128*32];

  int r0 = t >> 2;
  int kc = ((t&3) - r0) & 3;
  int ko = kc*8;
  int mg0 = tm*128 + r0, mg1 = mg0 + 64;
  int p0 = perm[e*NPAIRS + min(mg0, me-1)];
  int p1 = perm[e*NPAIRS + min(mg1, me-1)];
  const u16* arow0 = act + (size_t)p0*INTER + ko;
  const u16* arow1 = act + (size_t)p1*INTER + ko;
  int j0 = tn*128 + r0, j1 = j0 + 64;
  const u16* brow0 = wdb + ((size_t)e*HIDDEN + j0)*INTER + ko;
  const u16* brow1 = wdb + ((size_t)e*HIDDEN + j1)*INTER + ko;

  int wvb = (t>>6)*512;
  u16* Asw0 = &As[wvb];
  u16* Asw1 = &As[2048 + wvb];
  u16* Bsw0 = &Bs[wvb];
  u16* Bsw1 = &Bs[2048 + wvb];

  int wv = t>>6, lane = t&63;
  int wm = wv>>1, wn = wv&1;
  int l15 = lane&15, q = lane>>4;

  f32x4 acc[4][4] = {};
  int aoff[4], boff[4];
  #pragma unroll
  for (int i=0;i<4;++i){ int row = wm*64 + i*16 + l15; aoff[i] = row*32 + ((q+row)&3)*8; }
  #pragma unroll
  for (int j=0;j<4;++j){ int row = wn*64 + j*16 + l15; boff[j] = row*32 + ((q+row)&3)*8; }

  auto mma = [&](){
    bf16x8 af[4], bfr[4];
    #pragma unroll
    for (int i=0;i<4;++i){ af[i] = *(const bf16x8*)&As[aoff[i]]; bfr[i] = *(const bf16x8*)&Bs[boff[i]]; }
    #pragma unroll
    for (int i=0;i<4;++i)
      #pragma unroll
      for (int j=0;j<4;++j)
        acc[i][j] = __builtin_amdgcn_mfma_f32_16x16x32_bf16(af[i], bfr[j], acc[i][j],0,0,0);
  };

  int kt0 = ks*22, kt1 = kt0 + 22;   // INTER/32 = 88 = 4*22
  for (int kt = kt0; kt < kt1; ++kt){
    __syncthreads();
    gl16(arow0 + kt*32, Asw0);
    gl16(arow1 + kt*32, Asw1);
    gl16(brow0 + kt*32, Bsw0);
    gl16(brow1 + kt*32, Bsw1);
    __syncthreads();
    mma();
  }
  if (ks == 3){
    int aid = kc>>1, rr = (kc&1)*8;
    __syncthreads();
    gl16(zd + (size_t)p0*32 + ko, Asw0);
    gl16(zd + (size_t)p1*32 + ko, Asw1);
    gl16(dbb + ((size_t)(aid*NEXP+e)*HIDDEN + j0)*MAXRANK + rr, Bsw0);
    gl16(dbb + ((size_t)(aid*NEXP+e)*HIDDEN + j1)*MAXRANK + rr, Bsw1);
    __syncthreads();
    mma();
  }

  int col = l15, quad = q;
  #pragma unroll
  for (int i = 0; i < 4; ++i){
    #pragma unroll
    for (int r = 0; r < 4; ++r){
      int mg = tm*128 + wm*64 + i*16 + quad*4 + r;
      if (mg < me){
        int p = perm[e*NPAIRS + mg];
        float wp = tw[p];
        size_t base = (size_t)(p >> 1)*HIDDEN;
        #pragma unroll
        for (int j = 0; j < 4; ++j){
          int jc = tn*128 + wn*64 + j*16 + col;
          atomicAdd(&outf[base + jc], wp * acc[i][j][r]);
        }
      }
    }
  }
}

// ===================== FALLBACK PATH (round-3 verified kernels, f32 weights) =====================
__global__ __launch_bounds__(256) void k_gufused(
    const float* __restrict__ x, const float* __restrict__ wgu,
    const float* __restrict__ gate_b, const float* __restrict__ up_b,
    const u16* __restrict__ zg, const u16* __restrict__ zu,
    const int* __restrict__ cnt, const int* __restrict__ perm,
    u16* __restrict__ act)
{
  int e = blockIdx.z;
  int me = cnt[e];
  int tm = blockIdx.y;
  if (tm*128 >= me) return;
  int tn = blockIdx.x;
  int t = threadIdx.x;

  __shared__ __align__(16) u16 As[128*32];
  __shared__ __align__(16) u16 Bg[64*32];
  __shared__ __align__(16) u16 Bu[64*32];

  int r0 = t >> 2, cc = t & 3;
  int mg0 = tm*128 + r0, mg1 = mg0 + 64;
  int p0 = perm[e*NPAIRS + min(mg0, me-1)];
  int p1 = perm[e*NPAIRS + min(mg1, me-1)];
  const float* arow0 = x + (size_t)(p0 >> 1)*HIDDEN;
  const float* arow1 = x + (size_t)(p1 >> 1)*HIDDEN;
  int jg = tn*64 + r0;
  const float* browg = wgu + ((size_t)e*NGU + jg)*HIDDEN;
  const float* browu = wgu + ((size_t)e*NGU + INTER + jg)*HIDDEN;

  int wv = t >> 6, lane = t & 63;
  int wm = wv >> 1, wn = wv & 1;

  f32x4 accg[4][2] = {};
  f32x4 accu[4][2] = {};
  int aoff[4], boff[2];
  #pragma unroll
  for (int i = 0; i < 4; ++i) aoff[i] = (wm*64 + i*16 + (lane&15))*32 + (lane>>4)*8;
  #pragma unroll
  for (int j = 0; j < 2; ++j) boff[j] = (wn*32 + j*16 + (lane&15))*32 + (lane>>4)*8;

  for (int kt = 0; kt < HIDDEN/32; ++kt){
    uint4 a0 = cvt8(arow0 + kt*32 + cc*8);
    uint4 a1 = cvt8(arow1 + kt*32 + cc*8);
    uint4 bg = cvt8(browg + kt*32 + cc*8);
    uint4 bu = cvt8(browu + kt*32 + cc*8);
    __syncthreads();
    *(uint4*)&As[r0*32 + cc*8]      = a0;
    *(uint4*)&As[(r0+64)*32 + cc*8] = a1;
    *(uint4*)&Bg[r0*32 + cc*8]      = bg;
    *(uint4*)&Bu[r0*32 + cc*8]      = bu;
    __syncthreads();
    bf16x8 af[4], bgf[2], buf[2];
    #pragma unroll
    for (int i = 0; i < 4; ++i) af[i] = *(const bf16x8*)&As[aoff[i]];
    #pragma unroll
    for (int j = 0; j < 2; ++j){ bgf[j] = *(const bf16x8*)&Bg[boff[j]]; buf[j] = *(const bf16x8*)&Bu[boff[j]]; }
    #pragma unroll
    for (int i = 0; i < 4; ++i)
      #pragma unroll
      for (int j = 0; j < 2; ++j){
        accg[i][j] = __builtin_amdgcn_mfma_f32_16x16x32_bf16(af[i], bgf[j], accg[i][j], 0, 0, 0);
        accu[i][j] = __builtin_amdgcn_mfma_f32_16x16x32_bf16(af[i], buf[j], accu[i][j], 0, 0, 0);
      }
  }
  {
    uint4 a0 = *(const uint4*)(zg + (size_t)p0*32 + cc*8);
    uint4 a1 = *(const uint4*)(zg + (size_t)p1*32 + cc*8);
    int aid = cc >> 1, rr = (cc & 1)*8;
    uint4 bg = cvt8(gate_b + ((size_t)(aid*NEXP + e)*INTER + jg)*MAXRANK + rr);
    __syncthreads();
    *(uint4*)&As[r0*32 + cc*8]      = a0;
    *(uint4*)&As[(r0+64)*32 + cc*8] = a1;
    *(uint4*)&Bg[r0*32 + cc*8]      = bg;
    __syncthreads();
    bf16x8 af[4], bgf[2];
    #pragma unroll
    for (int i = 0; i < 4; ++i) af[i] = *(const bf16x8*)&As[aoff[i]];
    #pragma unroll
    for (int j = 0; j < 2; ++j) bgf[j] = *(const bf16x8*)&Bg[boff[j]];
    #pragma unroll
    for (int i = 0; i < 4; ++i)
      #pragma unroll
      for (int j = 0; j < 2; ++j)
        accg[i][j] = __builtin_amdgcn_mfma_f32_16x16x32_bf16(af[i], bgf[j], accg[i][j], 0, 0, 0);
  }
  {
    uint4 a0 = *(const uint4*)(zu + (size_t)p0*32 + cc*8);
    uint4 a1 = *(const uint4*)(zu + (size_t)p1*32 + cc*8);
    int aid = cc >> 1, rr = (cc & 1)*8;
    uint4 bu = cvt8(up_b + ((size_t)(aid*NEXP + e)*INTER + jg)*MAXRANK + rr);
    __syncthreads();
    *(uint4*)&As[r0*32 + cc*8]      = a0;
    *(uint4*)&As[(r0+64)*32 + cc*8] = a1;
    *(uint4*)&Bg[r0*32 + cc*8]      = bu;
    __syncthreads();
    bf16x8 af[4], buf[2];
    #pragma unroll
    for (int i = 0; i < 4; ++i) af[i] = *(const bf16x8*)&As[aoff[i]];
    #pragma unroll
    for (int j = 0; j < 2; ++j) buf[j] = *(const bf16x8*)&Bg[boff[j]];
    #pragma unroll
    for (int i = 0; i < 4; ++i)
      #pragma unroll
      for (int j = 0; j < 2; ++j)
        accu[i][j] = __builtin_amdgcn_mfma_f32_16x16x32_bf16(af[i], buf[j], accu[i][j], 0, 0, 0);
  }
  int col = lane & 15, quad = lane >> 4;
  #pragma unroll
  for (int i = 0; i < 4; ++i){
    #pragma unroll
    for (int r = 0; r < 4; ++r){
      int mg = tm*128 + wm*64 + i*16 + quad*4 + r;
      if (mg < me){
        int p = perm[e*NPAIRS + mg];
        size_t base = (size_t)p*INTER;
        #pragma unroll
        for (int j = 0; j < 2; ++j){
          int jc = tn*64 + wn*32 + j*16 + col;
          float g = accg[i][j][r], u = accu[i][j][r];
          float s = g / (1.f + __expf(-g));
          act[base + jc] = f2bf(s*u);
        }
      }
    }
  }
}

__global__ __launch_bounds__(256) void k_gemm_down(
    const u16* __restrict__ act, const float* __restrict__ wd,
    const float* __restrict__ down_b, const u16* __restrict__ zd,
    const float* __restrict__ tw,
    const int* __restrict__ cnt, const int* __restrict__ perm,
    float* __restrict__ outf)
{
  int e = blockIdx.z;
  int me = cnt[e];
  int tm = blockIdx.y;
  if (tm*128 >= me) return;
  int tn = blockIdx.x;
  int t = threadIdx.x;

  __shared__ __align__(16) u16 As[128*32];
  __shared__ __align__(16) u16 Bs[128*32];

  int r0 = t >> 2, cc = t & 3;
  int mg0 = tm*128 + r0, mg1 = mg0 + 64;
  int p0 = perm[e*NPAIRS + min(mg0, me-1)];
  int p1 = perm[e*NPAIRS + min(mg1, me-1)];
  const u16* arow0 = act + (size_t)p0*INTER;
  const u16* arow1 = act + (size_t)p1*INTER;
  int j0 = tn*128 + r0, j1 = j0 + 64;
  const float* brow0 = wd + ((size_t)e*HIDDEN + j0)*INTER;
  const float* brow1 = wd + ((size_t)e*HIDDEN + j1)*INTER;

  int wv = t >> 6, lane = t & 63;
  int wm = wv >> 1, wn = wv & 1;

  f32x4 acc[4][4] = {};
  int aoff[4], boff[4];
  #pragma unroll
  for (int i = 0; i < 4; ++i){
    aoff[i] = (wm*64 + i*16 + (lane&15))*32 + (lane>>4)*8;
    boff[i] = (wn*64 + i*16 + (lane&15))*32 + (lane>>4)*8;
  }

  auto compute = [&](){
    bf16x8 af[4], bfr[4];
    #pragma unroll
    for (int i = 0; i < 4; ++i){
      af[i]  = *(const bf16x8*)&As[aoff[i]];
      bfr[i] = *(const bf16x8*)&Bs[boff[i]];
    }
    #pragma unroll
    for (int i = 0; i < 4; ++i)
      #pragma unroll
      for (int j = 0; j < 4; ++j)
        acc[i][j] = __builtin_amdgcn_mfma_f32_16x16x32_bf16(af[i], bfr[j], acc[i][j], 0, 0, 0);
  };

  for (int kt = 0; kt < INTER/32; ++kt){
    uint4 a0 = *(const uint4*)(arow0 + kt*32 + cc*8);
    uint4 a1 = *(const uint4*)(arow1 + kt*32 + cc*8);
    uint4 b0 = cvt8(brow0 + kt*32 + cc*8);
    uint4 b1 = cvt8(brow1 + kt*32 + cc*8);
    __syncthreads();
    *(uint4*)&As[r0*32 + cc*8]      = a0;
    *(uint4*)&As[(r0+64)*32 + cc*8] = a1;
    *(uint4*)&Bs[r0*32 + cc*8]      = b0;
    *(uint4*)&Bs[(r0+64)*32 + cc*8] = b1;
    __syncthreads();
    compute();
  }
  {
    uint4 a0 = *(const uint4*)(zd + (size_t)p0*32 + cc*8);
    uint4 a1 = *(const uint4*)(zd + (size_t)p1*32 + cc*8);
    int aid = cc >> 1, rr = (cc & 1)*8;
    uint4 b0 = cvt8(down_b + ((size_t)(aid*NEXP + e)*HIDDEN + j0)*MAXRANK + rr);
    uint4 b1 = cvt8(down_b + ((size_t)(aid*NEXP + e)*HIDDEN + j1)*MAXRANK + rr);
    __syncthreads();
    *(uint4*)&As[r0*32 + cc*8]      = a0;
    *(uint4*)&As[(r0+64)*32 + cc*8] = a1;
    *(uint4*)&Bs[r0*32 + cc*8]      = b0;
    *(uint4*)&Bs[(r0+64)*32 + cc*8] = b1;
    __syncthreads();
    compute();
  }
  int col = lane & 15, quad = lane >> 4;
  #pragma unroll
  for (int i = 0; i < 4; ++i){
    #pragma unroll
    for (int r = 0; r < 4; ++r){
      int mg = tm*128 + wm*64 + i*16 + quad*4 + r;
      if (mg < me){
        int p = perm[e*NPAIRS + mg];
        float wp = tw[p];
        size_t base = (size_t)(p >> 1)*HIDDEN;
        #pragma unroll
        for (int j = 0; j < 4; ++j){
          int jc = tn*128 + wn*64 + j*16 + col;
          atomicAdd(&outf[base + jc], wp * acc[i][j][r]);
        }
      }
    }
  }
}

extern "C" void kernel_launch(void* const* d_in, const int* in_sizes, int n_in,
                              void* d_out, int out_size, void* d_ws, size_t ws_size,
                              hipStream_t stream){
  const float* x        = (const float*)d_in[0];
  const int*   topk_ids = (const int*)d_in[1];
  const float* tw       = (const float*)d_in[2];
  const float* gate_a   = (const float*)d_in[3];
  const float* gate_b   = (const float*)d_in[4];
  const float* up_a     = (const float*)d_in[5];
  const float* up_b     = (const float*)d_in[6];
  const float* down_a   = (const float*)d_in[7];
  const float* down_b   = (const float*)d_in[8];
  const int*   widx     = (const int*)d_in[9];
  const int*   seq_lens = (const int*)d_in[10];
  const int*   ranks    = (const int*)d_in[11];
  const float* scal     = (const float*)d_in[12];
  const float* wgu      = (const float*)d_in[13];
  const float* wd       = (const float*)d_in[14];
  float* outf = (float*)d_out;
  char* ws = (char*)d_ws;

  if (ws_size >= (size_t)FAST_NEED){
    int* cnt  = (int*)(ws + F_CNT);
    int* perm = (int*)(ws + F_PERM);
    u16* zg   = (u16*)(ws + F_ZG);
    u16* zu   = (u16*)(ws + F_ZU);
    u16* zd   = (u16*)(ws + F_ZD);
    u16* xb   = (u16*)(ws + F_XBF);
    u16* act  = (u16*)(ws + F_ACT);
    u16* gbb  = (u16*)(ws + F_GB);
    u16* ubb  = (u16*)(ws + F_UB);
    u16* dbb  = (u16*)(ws + F_DB);
    u16* wgub = (u16*)(ws + F_WGU);
    u16* wdb  = (u16*)(ws + F_WD);

    hipLaunchKernelGGL(k_zero,  dim3(N_TOK*HIDDEN/1024), dim3(256), 0, stream, outf, cnt);
    hipLaunchKernelGGL(k_route, dim3(16), dim3(256), 0, stream, topk_ids, cnt, perm);
    hipLaunchKernelGGL(k_cvt, dim3((N_TOK*HIDDEN/8+255)/256), dim3(256), 0, stream, x, xb, N_TOK*HIDDEN/8);
    hipLaunchKernelGGL(k_cvt, dim3((NEXP*NGU*HIDDEN/8+255)/256), dim3(256), 0, stream, wgu, wgub, NEXP*NGU*HIDDEN/8);
    hipLaunchKernelGGL(k_cvt, dim3((NEXP*HIDDEN*INTER/8+255)/256), dim3(256), 0, stream, wd, wdb, NEXP*HIDDEN*INTER/8);
    hipLaunchKernelGGL(k_cvt, dim3((NADAPT*NEXP*INTER*MAXRANK/8+255)/256), dim3(256), 0, stream, gate_b, gbb, NADAPT*NEXP*INTER*MAXRANK/8);
    hipLaunchKernelGGL(k_cvt, dim3((NADAPT*NEXP*INTER*MAXRANK/8+255)/256), dim3(256), 0, stream, up_b, ubb, NADAPT*NEXP*INTER*MAXRANK/8);
    hipLaunchKernelGGL(k_cvt, dim3((NADAPT*NEXP*HIDDEN*MAXRANK/8+255)/256), dim3(256), 0, stream, down_b, dbb, NADAPT*NEXP*HIDDEN*MAXRANK/8);
    hipLaunchKernelGGL(k_zgu, dim3(NPAIRS), dim3(256), 0, stream,
                       x, topk_ids, gate_a, up_a, widx, seq_lens, ranks, scal, zg, zu);
    hipLaunchKernelGGL(k_gufused_bf, dim3(INTER/64, 32, NEXP), dim3(256), 0, stream,
                       xb, wgub, gbb, ubb, zg, zu, cnt, perm, act);
    hipLaunchKernelGGL(k_zd, dim3(NPAIRS), dim3(256), 0, stream,
                       act, topk_ids, down_a, widx, seq_lens, ranks, scal, zd);
    hipLaunchKernelGGL(k_down_bf, dim3(32, 32, NEXP), dim3(256), 0, stream,
                       act, wdb, dbb, zd, tw, cnt, perm, outf);
  } else {
    int* cnt  = (int*)(ws + B_CNT);
    int* perm = (int*)(ws + B_PERM);
    u16* zg   = (u16*)(ws + B_ZG);
    u16* zu   = (u16*)(ws + B_ZU);
    u16* zd   = (u16*)(ws + B_ZD);
    u16* act  = (u16*)(ws + B_ACT);

    hipLaunchKernelGGL(k_zero,  dim3(N_TOK*HIDDEN/1024), dim3(256), 0, stream, outf, cnt);
    hipLaunchKernelGGL(k_route, dim3(16), dim3(256), 0, stream, topk_ids, cnt, perm);
    hipLaunchKernelGGL(k_zgu,   dim3(NPAIRS), dim3(256), 0, stream,
                       x, topk_ids, gate_a, up_a, widx, seq_lens, ranks, scal, zg, zu);
    hipLaunchKernelGGL(k_gufused, dim3(INTER/64, 32, NEXP), dim3(256), 0, stream,
                       x, wgu, gate_b, up_b, zg, zu, cnt, perm, act);
    hipLaunchKernelGGL(k_zd,    dim3(NPAIRS), dim3(256), 0, stream,
                       act, topk_ids, down_a, widx, seq_lens, ranks, scal, zd);
    hipLaunchKernelGGL(k_gemm_down, dim3(HIDDEN/128, 32, NEXP), dim3(256), 0, stream,
                       act, wd, down_b, zd, tw, cnt, perm, outf);
  }
}